// Round 16
// baseline (208.944 us; speedup 1.0000x reference)
//
#include <hip/hip_runtime.h>
#include <hip/hip_bf16.h>

typedef __attribute__((ext_vector_type(4))) float f32x4;
typedef __attribute__((ext_vector_type(8))) short bf16x8;
typedef __attribute__((ext_vector_type(4))) short short4v;

#define DEVI __device__ __forceinline__

constexpr int Bc = 2, Tc = 2048, Dc = 2048, Hc = 32, KVc = 8, HDc = 64;
constexpr int GRP = Hc / KVc;  // 4
constexpr float EPSc = 1e-6f;
// SCALE * log2(e) folded into Q so softmax uses exp2
constexpr float QMULT = 0.125f * 1.4426950408889634f;
constexpr float INV2PI = 0.15915494309189535f;
constexpr float ROPE_C = 0.41524101186092029f;  // log2(10000)/32

DEVI short f2b(float f) {
    __hip_bfloat16 h = __float2bfloat16(f);
    short s;
    __builtin_memcpy(&s, &h, sizeof(short));
    return s;
}
DEVI float b2f(short s) {
    unsigned int u = ((unsigned int)(unsigned short)s) << 16;
    float f;
    __builtin_memcpy(&f, &u, sizeof(float));
    return f;
}

#define GLOAD16(g, l)                                                        \
    __builtin_amdgcn_global_load_lds(                                        \
        (const __attribute__((address_space(1))) void*)(g),                  \
        (__attribute__((address_space(3))) void*)(l), 16, 0, 0)

// ---------------------------------------------------------------------------
// prep: weight transposes f32 (2048 x C) -> bf16 (C x 2048) (z=0..3) and
// x f32 -> bf16 convert (z=4), one launch.  grid (32, 32, 5).
// ---------------------------------------------------------------------------
__global__ __launch_bounds__(256) void prep_all(const float* __restrict__ x,
                                                const float* __restrict__ Wq,
                                                const float* __restrict__ Wk,
                                                const float* __restrict__ Wv,
                                                const float* __restrict__ Wo,
                                                short* __restrict__ xb,
                                                short* __restrict__ WqkvT,
                                                short* __restrict__ WoT) {
    const int z = blockIdx.z;
    if (z == 4) {  // convert x: 8.4M elems, 1024 blocks, 4 passes of 8/thread
        size_t base = ((size_t)(blockIdx.y * 32 + blockIdx.x) * 256 + threadIdx.x) * 8;
#pragma unroll
        for (int p = 0; p < 4; ++p) {
            size_t i = base + (size_t)p * 2097152;
            float4 a = *reinterpret_cast<const float4*>(x + i);
            float4 b = *reinterpret_cast<const float4*>(x + i + 4);
            bf16x8 o = {f2b(a.x), f2b(a.y), f2b(a.z), f2b(a.w),
                        f2b(b.x), f2b(b.y), f2b(b.z), f2b(b.w)};
            *reinterpret_cast<bf16x8*>(xb + i) = o;
        }
        return;
    }
    const float* src;
    short* dst;
    int C;
    if (z == 0)      { src = Wq; dst = WqkvT;                          C = 2048; }
    else if (z == 1) { src = Wk; dst = WqkvT + (size_t)2048 * 2048;    C = 512; }
    else if (z == 2) { src = Wv; dst = WqkvT + (size_t)2560 * 2048;    C = 512; }
    else             { src = Wo; dst = WoT;                            C = 2048; }
    const int n0 = blockIdx.x * 64, k0 = blockIdx.y * 64;
    if (n0 >= C) return;

    __shared__ __align__(16) short t[64][72];
    const int rl = threadIdx.x >> 2, q = threadIdx.x & 3;
#pragma unroll
    for (int jj = 0; jj < 4; ++jj) {
        float4 v = *reinterpret_cast<const float4*>(src + (size_t)(k0 + rl) * C + n0 + q * 16 + jj * 4);
        short4v s = {f2b(v.x), f2b(v.y), f2b(v.z), f2b(v.w)};
        *reinterpret_cast<short4v*>(&t[rl][q * 16 + jj * 4]) = s;
    }
    __syncthreads();
    alignas(16) short buf[16];
#pragma unroll
    for (int e = 0; e < 16; ++e) buf[e] = t[q * 16 + e][rl];
    short* d = dst + (size_t)(n0 + rl) * 2048 + k0 + q * 16;
    *reinterpret_cast<int4*>(d) = reinterpret_cast<int4*>(buf)[0];
    *reinterpret_cast<int4*>(d + 8) = reinterpret_cast<int4*>(buf)[1];
}

// bijective XCD swizzle of flattened block id (nwg % 8 == 0)
DEVI void xcd_swizzle(int nx, int& bx, int& by) {
    int nwg = nx * gridDim.y;
    int fb = by * nx + bx;
    int cpx = nwg >> 3;
    int swz = (fb & 7) * cpx + (fb >> 3);
    by = swz / nx;
    bx = swz - by * nx;
}

// ---------------------------------------------------------------------------
// QKV-projection GEMM with fused RMSNorm+RoPE epilogue and fused V-transpose.
// C(4096x3072) = xb(4096x2048) * WqkvT(3072x2048)^T, 128x128 tile, BK=32,
// dbuf LDS (32 KB -> 5 blocks/CU), counted vmcnt(4), XOR chunk-swizzle
// (chunk ^= (row>>1)&3 -> max 2-way bank alias, free).  256 thr (4 waves).
// Epilogue: cols<2048 -> RMSNorm(qs)+RoPE+QMULT -> qb (B,H,T,64)
//           cols 2048-2559 -> RMSNorm(ks)+RoPE -> kb (B,KV,T,64)
//           cols>=2560 -> transposed bf16 tiles vt[b][kv][tile][d64][t64]
// ---------------------------------------------------------------------------
__global__ __launch_bounds__(256) void gemm_proj(const short* __restrict__ A,
                                                 const short* __restrict__ Bt,
                                                 const float* __restrict__ qs,
                                                 const float* __restrict__ ks,
                                                 short* __restrict__ qb,
                                                 short* __restrict__ kb,
                                                 short* __restrict__ vt) {
    constexpr int K = 2048;
    __shared__ __align__(16) short sA[2][128 * 32];
    __shared__ __align__(16) short sB[2][128 * 32];

    const int tid = threadIdx.x;
    const int wave = tid >> 6, lane = tid & 63;
    const int lhi = lane >> 4, llo = lane & 15;
    int bx = blockIdx.x, by = blockIdx.y;
    xcd_swizzle(24, bx, by);
    const int bm = by * 128, bn = bx * 128;
    const int wm = (wave >> 1) * 64, wn = (wave & 1) * 64;

    // staging: chunk id c = l*256+tid in [0,512); row = c>>2, in-row chunk
    // (c&3), source chunk pre-swizzled by ^((row>>1)&3); LDS dest linear.
    const short* apt[2];
    const short* bpt[2];
#pragma unroll
    for (int l = 0; l < 2; ++l) {
        int c = l * 256 + tid;
        int r = c >> 2, ck = (c & 3) ^ ((r >> 1) & 3);
        apt[l] = A + (size_t)(bm + r) * K + ck * 8;
        bpt[l] = Bt + (size_t)(bn + r) * K + ck * 8;
    }

    f32x4 acc[4][4] = {};

#pragma unroll
    for (int l = 0; l < 2; ++l) {
        GLOAD16(apt[l], &sA[0][(l * 256 + tid) * 8]);
        GLOAD16(bpt[l], &sB[0][(l * 256 + tid) * 8]);
    }
    int c = 0;
    // read-side swizzled chunk offset (lane-constant): (row>>1)&3 == (llo>>1)&3
    const int co = ((lhi ^ ((llo >> 1) & 3)) << 3);

#pragma unroll 1
    for (int k0 = 0; k0 < K; k0 += 32) {
        if (k0 + 32 < K) {
            const int kn = k0 + 32;
#pragma unroll
            for (int l = 0; l < 2; ++l) {
                GLOAD16(apt[l] + kn, &sA[c ^ 1][(l * 256 + tid) * 8]);
                GLOAD16(bpt[l] + kn, &sB[c ^ 1][(l * 256 + tid) * 8]);
            }
            asm volatile("s_waitcnt vmcnt(4)" ::: "memory");
        } else {
            asm volatile("s_waitcnt vmcnt(0)" ::: "memory");
        }
        __builtin_amdgcn_s_barrier();
        asm volatile("" ::: "memory");

        bf16x8 af[4], bf[4];
#pragma unroll
        for (int i = 0; i < 4; ++i)
            af[i] = *reinterpret_cast<const bf16x8*>(&sA[c][(wm + i * 16 + llo) * 32 + co]);
#pragma unroll
        for (int j = 0; j < 4; ++j)
            bf[j] = *reinterpret_cast<const bf16x8*>(&sB[c][(wn + j * 16 + llo) * 32 + co]);
#pragma unroll
        for (int i = 0; i < 4; ++i)
#pragma unroll
            for (int j = 0; j < 4; ++j)
                acc[i][j] = __builtin_amdgcn_mfma_f32_16x16x32_bf16(af[i], bf[j], acc[i][j], 0, 0, 0);

        asm volatile("" ::: "memory");
        __builtin_amdgcn_s_barrier();
        c ^= 1;
    }

    // ---- fused epilogue ----
    const int rm = bm + wm;       // wave's first output row (64-aligned)
    const int b = rm >> 11;
    const int tb = rm & 2047;
    const int col0 = bn + wn;     // wave's first output col (64-aligned)

    if (col0 < 2560) {
        const bool isq = col0 < 2048;
        const float* scale = isq ? qs : ks;
        const float mult = isq ? QMULT : 1.0f;
        float scl[4];
#pragma unroll
        for (int j = 0; j < 4; ++j) scl[j] = scale[j * 16 + llo];
        short* outp;
        if (isq)
            outp = qb + (size_t)(b * Hc + (col0 >> 6)) * 2048 * 64;
        else
            outp = kb + (size_t)(b * KVc + ((col0 - 2048) >> 6)) * 2048 * 64;
        // per-lane RoPE revolution factors: i_rope = (j&1)*16 + llo
        const float ir0 = INV2PI * exp2f(-ROPE_C * (float)llo);
        const float ir1 = INV2PI * exp2f(-ROPE_C * (float)(16 + llo));
#pragma unroll
        for (int i = 0; i < 4; ++i)
#pragma unroll
            for (int r = 0; r < 4; ++r) {
                float ss = 0.f;
#pragma unroll
                for (int j = 0; j < 4; ++j) ss += acc[i][j][r] * acc[i][j][r];
                ss += __shfl_xor(ss, 1);
                ss += __shfl_xor(ss, 2);
                ss += __shfl_xor(ss, 4);
                ss += __shfl_xor(ss, 8);
                float rinv = 1.0f / sqrtf(ss * (1.0f / 64.0f) + EPSc);
                float vn[4];
#pragma unroll
                for (int j = 0; j < 4; ++j) vn[j] = acc[i][j][r] * rinv * scl[j];
                const int t = tb + i * 16 + lhi * 4 + r;
                float f0 = (float)t * ir0;
                f0 -= floorf(f0);
                float f1 = (float)t * ir1;
                f1 -= floorf(f1);
                float sn0 = __builtin_amdgcn_sinf(f0), cs0 = __builtin_amdgcn_cosf(f0);
                float sn1 = __builtin_amdgcn_sinf(f1), cs1 = __builtin_amdgcn_cosf(f1);
                size_t base = (size_t)t * 64 + llo;
                outp[base]      = f2b((vn[0] * cs0 - vn[2] * sn0) * mult);
                outp[base + 16] = f2b((vn[1] * cs1 - vn[3] * sn1) * mult);
                outp[base + 32] = f2b((vn[2] * cs0 + vn[0] * sn0) * mult);
                outp[base + 48] = f2b((vn[3] * cs1 + vn[1] * sn1) * mult);
            }
    } else {
        // V: write transposed tile directly: vt[b][kv][tile][d(64)][t(64)]
        const int kv = (col0 - 2560) >> 6;
        const int tile = tb >> 6;   // rm 64-aligned -> one tile per wave
        short* dst = vt + ((size_t)(b * 8 + kv) * 32 + tile) * 4096;
#pragma unroll
        for (int i = 0; i < 4; ++i)
#pragma unroll
            for (int j = 0; j < 4; ++j) {
                short4v p4 = {f2b(acc[i][j][0]), f2b(acc[i][j][1]),
                              f2b(acc[i][j][2]), f2b(acc[i][j][3])};
                *reinterpret_cast<short4v*>(
                    &dst[(j * 16 + llo) * 64 + i * 16 + lhi * 4]) = p4;
            }
    }
}

// ---------------------------------------------------------------------------
// GEMM: C(MxN) = A(MxK,bf16) * Bt(NxK,bf16)^T  (used for output projection)
// 128x128 tile, BK=32, dbuf (32 KB -> 5 blocks/CU) + counted vmcnt(4) +
// XOR chunk-swizzle (chunk ^= (row>>1)&3).
// ---------------------------------------------------------------------------
template <typename CT>
__global__ __launch_bounds__(256) void gemm_bt(const short* __restrict__ A,
                                               const short* __restrict__ Bt,
                                               CT* __restrict__ C, int M, int N, int K) {
    __shared__ __align__(16) short sA[2][128 * 32];
    __shared__ __align__(16) short sB[2][128 * 32];

    const int tid = threadIdx.x;
    const int wave = tid >> 6, lane = tid & 63;
    const int lhi = lane >> 4, llo = lane & 15;
    int bx = blockIdx.x, by = blockIdx.y;
    xcd_swizzle(gridDim.x, bx, by);
    const int bm = by * 128, bn = bx * 128;
    const int wm = (wave >> 1) * 64, wn = (wave & 1) * 64;

    const short* apt[2];
    const short* bpt[2];
#pragma unroll
    for (int l = 0; l < 2; ++l) {
        int c = l * 256 + tid;
        int r = c >> 2, ck = (c & 3) ^ ((r >> 1) & 3);
        apt[l] = A + (size_t)(bm + r) * K + ck * 8;
        bpt[l] = Bt + (size_t)(bn + r) * K + ck * 8;
    }

    f32x4 acc[4][4] = {};

#pragma unroll
    for (int l = 0; l < 2; ++l) {
        GLOAD16(apt[l], &sA[0][(l * 256 + tid) * 8]);
        GLOAD16(bpt[l], &sB[0][(l * 256 + tid) * 8]);
    }
    int c = 0;
    const int co = ((lhi ^ ((llo >> 1) & 3)) << 3);

#pragma unroll 1
    for (int k0 = 0; k0 < K; k0 += 32) {
        if (k0 + 32 < K) {
            const int kn = k0 + 32;
#pragma unroll
            for (int l = 0; l < 2; ++l) {
                GLOAD16(apt[l] + kn, &sA[c ^ 1][(l * 256 + tid) * 8]);
                GLOAD16(bpt[l] + kn, &sB[c ^ 1][(l * 256 + tid) * 8]);
            }
            asm volatile("s_waitcnt vmcnt(4)" ::: "memory");
        } else {
            asm volatile("s_waitcnt vmcnt(0)" ::: "memory");
        }
        __builtin_amdgcn_s_barrier();
        asm volatile("" ::: "memory");

        bf16x8 af[4], bf[4];
#pragma unroll
        for (int i = 0; i < 4; ++i)
            af[i] = *reinterpret_cast<const bf16x8*>(&sA[c][(wm + i * 16 + llo) * 32 + co]);
#pragma unroll
        for (int j = 0; j < 4; ++j)
            bf[j] = *reinterpret_cast<const bf16x8*>(&sB[c][(wn + j * 16 + llo) * 32 + co]);
#pragma unroll
        for (int i = 0; i < 4; ++i)
#pragma unroll
            for (int j = 0; j < 4; ++j)
                acc[i][j] = __builtin_amdgcn_mfma_f32_16x16x32_bf16(af[i], bf[j], acc[i][j], 0, 0, 0);

        asm volatile("" ::: "memory");
        __builtin_amdgcn_s_barrier();
        c ^= 1;
    }

#pragma unroll
    for (int i = 0; i < 4; ++i)
#pragma unroll
        for (int j = 0; j < 4; ++j)
#pragma unroll
            for (int r = 0; r < 4; ++r) {
                size_t idx = (size_t)(bm + wm + i * 16 + lhi * 4 + r) * N + bn + wn + j * 16 + llo;
                if constexpr (sizeof(CT) == 2)
                    C[idx] = f2b(acc[i][j][r]);
                else
                    C[idx] = acc[i][j][r];
            }
}

// ---------------------------------------------------------------------------
// Flash attention, causal GQA, swapped-QK^T form, double-buffered K/V,
// defer-max online softmax.  8 thin waves x 16 q-rows (512 thr) per 128-row
// q-tile: halves the per-wave serial chain, 24 waves/CU (LDS 50.4KB).
// grid (64 hb, 16 qt-rank), longest q-tiles dispatched first (LPT).
// ---------------------------------------------------------------------------
__global__ __launch_bounds__(512) void attn_fwd(const short* __restrict__ Qb,
                                                const short* __restrict__ Kb,
                                                const short* __restrict__ Vt,
                                                short* __restrict__ Ob) {
    __shared__ __align__(16) short sK[2][64 * 64];
    __shared__ __align__(16) short sV[2][64 * 64];
    __shared__ __align__(16) short sP[8][16 * 72];

    const int hb = blockIdx.x;           // h = hb & 31, b = hb >> 5
    const int qt = 15 - (int)blockIdx.y; // y=0 -> longest (qt=15) first
    const int h = hb & 31, b = hb >> 5;
    const int kvh = h >> 2;
    const int tid = threadIdx.x, wave = tid >> 6, lane = tid & 63;
    const int lhi = lane >> 4, llo = lane & 15;

    const short* Qp = Qb + (size_t)(b * Hc + h) * Tc * 64;
    const short* Kp = Kb + (size_t)(b * KVc + kvh) * Tc * 64;
    const short* Vp = Vt + (size_t)(b * KVc + kvh) * 32 * 4096;

    // staging: 512 threads cover one 64x64 tile; 1 K + 1 V GLOAD16 each
    const int srow = tid >> 3, sslot = tid & 7;
    const int soff = (sslot ^ (srow & 7)) * 8;

    const int Q0 = qt * 128 + wave * 16;     // this wave's 16 q rows
    const int ktmax_w = (Q0 + 15) >> 6;
    const int nkt = 2 * qt + 2;

    bf16x8 qf[2];
#pragma unroll
    for (int kk = 0; kk < 2; ++kk)
        qf[kk] = *reinterpret_cast<const bf16x8*>(
            Qp + (size_t)(Q0 + llo) * 64 + kk * 32 + lhi * 8);

    f32x4 o[4] = {};
    float mreg = -1e30f;
    float lreg = 0.f;

    {
        GLOAD16(Kp + (size_t)srow * 64 + soff, &sK[0][tid * 8]);
        GLOAD16(Vp + (size_t)srow * 64 + soff, &sV[0][tid * 8]);
    }
    int c = 0;

#pragma unroll 1
    for (int kt = 0; kt < nkt; ++kt) {
        const bool has_next = (kt + 1) < nkt;
        if (has_next) {
            const size_t kbase = (size_t)(kt + 1) * 4096;
            GLOAD16(Kp + kbase + srow * 64 + soff, &sK[c ^ 1][tid * 8]);
            GLOAD16(Vp + kbase + srow * 64 + soff, &sV[c ^ 1][tid * 8]);
            asm volatile("s_waitcnt vmcnt(2)" ::: "memory");
        } else {
            asm volatile("s_waitcnt vmcnt(0)" ::: "memory");
        }
        __builtin_amdgcn_s_barrier();
        asm volatile("" ::: "memory");  // keep ds_reads below the barrier

        if (kt <= ktmax_w) {
            const short* sKc = sK[c];
            const short* sVc = sV[c];
            // S^T = K Q^T : st[n] has C[kv=16n+4lhi+r][q=llo]
            f32x4 st[4];
            __builtin_amdgcn_s_setprio(1);
#pragma unroll
            for (int n = 0; n < 4; ++n) {
                int krow = n * 16 + llo;
                bf16x8 ka0 = *reinterpret_cast<const bf16x8*>(
                    &sKc[krow * 64 + ((lhi ^ (krow & 7)) << 3)]);
                bf16x8 ka1 = *reinterpret_cast<const bf16x8*>(
                    &sKc[krow * 64 + (((4 + lhi) ^ (krow & 7)) << 3)]);
                f32x4 z = {0.f, 0.f, 0.f, 0.f};
                st[n] = __builtin_amdgcn_mfma_f32_16x16x32_bf16(ka0, qf[0], z, 0, 0, 0);
                st[n] = __builtin_amdgcn_mfma_f32_16x16x32_bf16(ka1, qf[1], st[n], 0, 0, 0);
            }
            __builtin_amdgcn_s_setprio(0);
            if (kt == ktmax_w) {  // causal mask (diagonal region only)
                int qg = Q0 + llo;
#pragma unroll
                for (int n = 0; n < 4; ++n)
#pragma unroll
                    for (int r = 0; r < 4; ++r) {
                        int kvg = kt * 64 + n * 16 + lhi * 4 + r;
                        if (kvg > qg) st[n][r] = -1e30f;
                    }
            }
            // per-row tile max (each lane owns row q = Q0 + llo)
            float r0 = fmaxf(fmaxf(st[0][0], st[0][1]), fmaxf(st[0][2], st[0][3]));
            float r1 = fmaxf(fmaxf(st[1][0], st[1][1]), fmaxf(st[1][2], st[1][3]));
            float r2 = fmaxf(fmaxf(st[2][0], st[2][1]), fmaxf(st[2][2], st[2][3]));
            float r3 = fmaxf(fmaxf(st[3][0], st[3][1]), fmaxf(st[3][2], st[3][3]));
            float pm = fmaxf(fmaxf(r0, r1), fmaxf(r2, r3));
            pm = fmaxf(pm, __shfl_xor(pm, 16));
            pm = fmaxf(pm, __shfl_xor(pm, 32));
            // defer-max: only rescale when tile max grew past running max + 8
            bool defer = __all(pm - mreg <= 8.f);
            if (!defer) {
                float mn = fmaxf(mreg, pm);
                float alpha = __builtin_amdgcn_exp2f(mreg - mn);
                mreg = mn;
                lreg *= alpha;
#pragma unroll
                for (int r = 0; r < 4; ++r) {
                    float ar = __shfl(alpha, lhi * 4 + r);
#pragma unroll
                    for (int j = 0; j < 4; ++j) o[j][r] *= ar;
                }
            }
            // P = exp2(S - m); row sum
            float ps = 0.f;
#pragma unroll
            for (int n = 0; n < 4; ++n)
#pragma unroll
                for (int r = 0; r < 4; ++r) {
                    float p = __builtin_amdgcn_exp2f(st[n][r] - mreg);
                    st[n][r] = p;
                    ps += p;
                }
            ps += __shfl_xor(ps, 16);
            ps += __shfl_xor(ps, 32);
            lreg += ps;
            // store P rows (16 x 64) to wave-private LDS (b64 stores)
#pragma unroll
            for (int n = 0; n < 4; ++n) {
                short4v p4 = {f2b(st[n][0]), f2b(st[n][1]), f2b(st[n][2]), f2b(st[n][3])};
                *reinterpret_cast<short4v*>(&sP[wave][llo * 72 + n * 16 + lhi * 4]) = p4;
            }
            // O += P V
            __builtin_amdgcn_s_setprio(1);
#pragma unroll
            for (int kk = 0; kk < 2; ++kk) {
                bf16x8 pa = *reinterpret_cast<const bf16x8*>(
                    &sP[wave][llo * 72 + kk * 32 + lhi * 8]);
#pragma unroll
                for (int j = 0; j < 4; ++j) {
                    int vrow = j * 16 + llo;
                    bf16x8 vf = *reinterpret_cast<const bf16x8*>(
                        &sVc[vrow * 64 + ((((kk * 4) + lhi) ^ (vrow & 7)) << 3)]);
                    o[j] = __builtin_amdgcn_mfma_f32_16x16x32_bf16(pa, vf, o[j], 0, 0, 0);
                }
            }
            __builtin_amdgcn_s_setprio(0);
        }
        asm volatile("" ::: "memory");  // keep ds_reads above the barrier
        __builtin_amdgcn_s_barrier();
        c ^= 1;
    }

    // epilogue: normalize, store bf16 (B,T,H*64)
    {
        float inv = 1.0f / lreg;
#pragma unroll
        for (int r = 0; r < 4; ++r) {
            float ivr = __shfl(inv, lhi * 4 + r);
            int qrow = Q0 + lhi * 4 + r;
#pragma unroll
            for (int j = 0; j < 4; ++j)
                Ob[((size_t)(b * Tc + qrow)) * 2048 + h * 64 + j * 16 + llo] =
                    f2b(o[j][r] * ivr);
        }
    }
}

// ---------------------------------------------------------------------------
extern "C" void kernel_launch(void* const* d_in, const int* in_sizes, int n_in,
                              void* d_out, int out_size, void* d_ws, size_t ws_size,
                              hipStream_t stream) {
    const float* x  = (const float*)d_in[0];
    const float* Wq = (const float*)d_in[1];
    const float* Wk = (const float*)d_in[2];
    const float* Wv = (const float*)d_in[3];
    const float* Wo = (const float*)d_in[4];
    const float* qs = (const float*)d_in[5];
    const float* ks = (const float*)d_in[6];
    float* out = (float*)d_out;

    char* w = (char*)d_ws;
    short* xb    = (short*)(w);                 // 16,777,216  (later: ob)
    short* WqkvT = (short*)(w + 16777216);      // 12,582,912
    short* WoT   = (short*)(w + 29360128);      //  8,388,608
    short* vt    = (short*)(w + 37748736);      //  8,388,608  (B,KV,32,64,64)
    short* qb    = (short*)(w + 62914560);      // 16,777,216
    short* kb    = (short*)(w + 79691776);      //  4,194,304
    short* ob    = xb;                          // alias (xb dead after proj)

    dim3 blk(256);
    // prep: x convert + all weight transposes in one launch
    prep_all<<<dim3(32, 32, 5), blk, 0, stream>>>(x, Wq, Wk, Wv, Wo, xb, WqkvT, WoT);
    // fused QKV projection + RMSNorm/RoPE epilogue + V-transpose -> qb, kb, vt
    gemm_proj<<<dim3(24, 32), blk, 0, stream>>>(xb, WqkvT, qs, ks, qb, kb, vt);
    // flash attention: 1024 blocks x 512 thr, longest q-tiles first (LPT)
    attn_fwd<<<dim3(64, 16), dim3(512), 0, stream>>>(qb, kb, vt, ob);
    // output projection (f32 out)
    gemm_bt<float><<<dim3(16, 32), blk, 0, stream>>>(ob, WoT, out, 4096, 2048, 2048);
}

// Round 17
// 199.626 us; speedup vs baseline: 1.0467x; 1.0467x over previous
//
#include <hip/hip_runtime.h>
#include <hip/hip_bf16.h>

typedef __attribute__((ext_vector_type(4))) float f32x4;
typedef __attribute__((ext_vector_type(8))) short bf16x8;
typedef __attribute__((ext_vector_type(4))) short short4v;

#define DEVI __device__ __forceinline__

constexpr int Bc = 2, Tc = 2048, Dc = 2048, Hc = 32, KVc = 8, HDc = 64;
constexpr int GRP = Hc / KVc;  // 4
constexpr float EPSc = 1e-6f;
// SCALE * log2(e) folded into Q so softmax uses exp2
constexpr float QMULT = 0.125f * 1.4426950408889634f;
constexpr float INV2PI = 0.15915494309189535f;
constexpr float ROPE_C = 0.41524101186092029f;  // log2(10000)/32

DEVI short f2b(float f) {
    __hip_bfloat16 h = __float2bfloat16(f);
    short s;
    __builtin_memcpy(&s, &h, sizeof(short));
    return s;
}
DEVI float b2f(short s) {
    unsigned int u = ((unsigned int)(unsigned short)s) << 16;
    float f;
    __builtin_memcpy(&f, &u, sizeof(float));
    return f;
}

#define GLOAD16(g, l)                                                        \
    __builtin_amdgcn_global_load_lds(                                        \
        (const __attribute__((address_space(1))) void*)(g),                  \
        (__attribute__((address_space(3))) void*)(l), 16, 0, 0)

// ---------------------------------------------------------------------------
// prep: weight transposes f32 (2048 x C) -> bf16 (C x 2048) (z=0..3) and
// x f32 -> bf16 convert (z=4), one launch.  grid (32, 32, 5).
// ---------------------------------------------------------------------------
__global__ __launch_bounds__(256) void prep_all(const float* __restrict__ x,
                                                const float* __restrict__ Wq,
                                                const float* __restrict__ Wk,
                                                const float* __restrict__ Wv,
                                                const float* __restrict__ Wo,
                                                short* __restrict__ xb,
                                                short* __restrict__ WqkvT,
                                                short* __restrict__ WoT) {
    const int z = blockIdx.z;
    if (z == 4) {  // convert x: 8.4M elems, 1024 blocks, 4 passes of 8/thread
        size_t base = ((size_t)(blockIdx.y * 32 + blockIdx.x) * 256 + threadIdx.x) * 8;
#pragma unroll
        for (int p = 0; p < 4; ++p) {
            size_t i = base + (size_t)p * 2097152;
            float4 a = *reinterpret_cast<const float4*>(x + i);
            float4 b = *reinterpret_cast<const float4*>(x + i + 4);
            bf16x8 o = {f2b(a.x), f2b(a.y), f2b(a.z), f2b(a.w),
                        f2b(b.x), f2b(b.y), f2b(b.z), f2b(b.w)};
            *reinterpret_cast<bf16x8*>(xb + i) = o;
        }
        return;
    }
    const float* src;
    short* dst;
    int C;
    if (z == 0)      { src = Wq; dst = WqkvT;                          C = 2048; }
    else if (z == 1) { src = Wk; dst = WqkvT + (size_t)2048 * 2048;    C = 512; }
    else if (z == 2) { src = Wv; dst = WqkvT + (size_t)2560 * 2048;    C = 512; }
    else             { src = Wo; dst = WoT;                            C = 2048; }
    const int n0 = blockIdx.x * 64, k0 = blockIdx.y * 64;
    if (n0 >= C) return;

    __shared__ __align__(16) short t[64][72];
    const int rl = threadIdx.x >> 2, q = threadIdx.x & 3;
#pragma unroll
    for (int jj = 0; jj < 4; ++jj) {
        float4 v = *reinterpret_cast<const float4*>(src + (size_t)(k0 + rl) * C + n0 + q * 16 + jj * 4);
        short4v s = {f2b(v.x), f2b(v.y), f2b(v.z), f2b(v.w)};
        *reinterpret_cast<short4v*>(&t[rl][q * 16 + jj * 4]) = s;
    }
    __syncthreads();
    alignas(16) short buf[16];
#pragma unroll
    for (int e = 0; e < 16; ++e) buf[e] = t[q * 16 + e][rl];
    short* d = dst + (size_t)(n0 + rl) * 2048 + k0 + q * 16;
    *reinterpret_cast<int4*>(d) = reinterpret_cast<int4*>(buf)[0];
    *reinterpret_cast<int4*>(d + 8) = reinterpret_cast<int4*>(buf)[1];
}

// bijective XCD swizzle of flattened block id (nwg % 8 == 0)
DEVI void xcd_swizzle(int nx, int& bx, int& by) {
    int nwg = nx * gridDim.y;
    int fb = by * nx + bx;
    int cpx = nwg >> 3;
    int swz = (fb & 7) * cpx + (fb >> 3);
    by = swz / nx;
    bx = swz - by * nx;
}

// ---------------------------------------------------------------------------
// QKV-projection GEMM with fused RMSNorm+RoPE epilogue and fused V-transpose.
// C(4096x3072) = xb(4096x2048) * WqkvT(3072x2048)^T, 128x128 tile, BK=32,
// dbuf LDS (32 KB -> 5 blocks/CU; grid 768 = 3/CU resident), counted
// vmcnt(4), XOR chunk-swizzle (chunk ^= (row>>1)&3, conflict-free).
// Epilogue: cols<2048 -> RMSNorm(qs)+RoPE+QMULT -> qb (B,H,T,64)
//           cols 2048-2559 -> RMSNorm(ks)+RoPE -> kb (B,KV,T,64)
//           cols>=2560 -> transposed bf16 tiles vt[b][kv][tile][d64][t64]
// ---------------------------------------------------------------------------
__global__ __launch_bounds__(256) void gemm_proj(const short* __restrict__ A,
                                                 const short* __restrict__ Bt,
                                                 const float* __restrict__ qs,
                                                 const float* __restrict__ ks,
                                                 short* __restrict__ qb,
                                                 short* __restrict__ kb,
                                                 short* __restrict__ vt) {
    constexpr int K = 2048;
    __shared__ __align__(16) short sA[2][128 * 32];
    __shared__ __align__(16) short sB[2][128 * 32];

    const int tid = threadIdx.x;
    const int wave = tid >> 6, lane = tid & 63;
    const int lhi = lane >> 4, llo = lane & 15;
    int bx = blockIdx.x, by = blockIdx.y;
    xcd_swizzle(24, bx, by);
    const int bm = by * 128, bn = bx * 128;
    const int wm = (wave >> 1) * 64, wn = (wave & 1) * 64;

    const short* apt[2];
    const short* bpt[2];
#pragma unroll
    for (int l = 0; l < 2; ++l) {
        int c = l * 256 + tid;
        int r = c >> 2, ck = (c & 3) ^ ((r >> 1) & 3);
        apt[l] = A + (size_t)(bm + r) * K + ck * 8;
        bpt[l] = Bt + (size_t)(bn + r) * K + ck * 8;
    }

    f32x4 acc[4][4] = {};

#pragma unroll
    for (int l = 0; l < 2; ++l) {
        GLOAD16(apt[l], &sA[0][(l * 256 + tid) * 8]);
        GLOAD16(bpt[l], &sB[0][(l * 256 + tid) * 8]);
    }
    int c = 0;
    const int co = ((lhi ^ ((llo >> 1) & 3)) << 3);

#pragma unroll 1
    for (int k0 = 0; k0 < K; k0 += 32) {
        if (k0 + 32 < K) {
            const int kn = k0 + 32;
#pragma unroll
            for (int l = 0; l < 2; ++l) {
                GLOAD16(apt[l] + kn, &sA[c ^ 1][(l * 256 + tid) * 8]);
                GLOAD16(bpt[l] + kn, &sB[c ^ 1][(l * 256 + tid) * 8]);
            }
            asm volatile("s_waitcnt vmcnt(4)" ::: "memory");
        } else {
            asm volatile("s_waitcnt vmcnt(0)" ::: "memory");
        }
        __builtin_amdgcn_s_barrier();
        asm volatile("" ::: "memory");

        bf16x8 af[4], bf[4];
#pragma unroll
        for (int i = 0; i < 4; ++i)
            af[i] = *reinterpret_cast<const bf16x8*>(&sA[c][(wm + i * 16 + llo) * 32 + co]);
#pragma unroll
        for (int j = 0; j < 4; ++j)
            bf[j] = *reinterpret_cast<const bf16x8*>(&sB[c][(wn + j * 16 + llo) * 32 + co]);
#pragma unroll
        for (int i = 0; i < 4; ++i)
#pragma unroll
            for (int j = 0; j < 4; ++j)
                acc[i][j] = __builtin_amdgcn_mfma_f32_16x16x32_bf16(af[i], bf[j], acc[i][j], 0, 0, 0);

        asm volatile("" ::: "memory");
        __builtin_amdgcn_s_barrier();
        c ^= 1;
    }

    // ---- fused epilogue ----
    const int rm = bm + wm;       // wave's first output row (64-aligned)
    const int b = rm >> 11;
    const int tb = rm & 2047;
    const int col0 = bn + wn;     // wave's first output col (64-aligned)

    if (col0 < 2560) {
        const bool isq = col0 < 2048;
        const float* scale = isq ? qs : ks;
        const float mult = isq ? QMULT : 1.0f;
        float scl[4];
#pragma unroll
        for (int j = 0; j < 4; ++j) scl[j] = scale[j * 16 + llo];
        short* outp;
        if (isq)
            outp = qb + (size_t)(b * Hc + (col0 >> 6)) * 2048 * 64;
        else
            outp = kb + (size_t)(b * KVc + ((col0 - 2048) >> 6)) * 2048 * 64;
        // per-lane RoPE revolution factors: i_rope = (j&1)*16 + llo
        const float ir0 = INV2PI * exp2f(-ROPE_C * (float)llo);
        const float ir1 = INV2PI * exp2f(-ROPE_C * (float)(16 + llo));
#pragma unroll
        for (int i = 0; i < 4; ++i)
#pragma unroll
            for (int r = 0; r < 4; ++r) {
                float ss = 0.f;
#pragma unroll
                for (int j = 0; j < 4; ++j) ss += acc[i][j][r] * acc[i][j][r];
                ss += __shfl_xor(ss, 1);
                ss += __shfl_xor(ss, 2);
                ss += __shfl_xor(ss, 4);
                ss += __shfl_xor(ss, 8);
                float rinv = 1.0f / sqrtf(ss * (1.0f / 64.0f) + EPSc);
                float vn[4];
#pragma unroll
                for (int j = 0; j < 4; ++j) vn[j] = acc[i][j][r] * rinv * scl[j];
                const int t = tb + i * 16 + lhi * 4 + r;
                float f0 = (float)t * ir0;
                f0 -= floorf(f0);
                float f1 = (float)t * ir1;
                f1 -= floorf(f1);
                float sn0 = __builtin_amdgcn_sinf(f0), cs0 = __builtin_amdgcn_cosf(f0);
                float sn1 = __builtin_amdgcn_sinf(f1), cs1 = __builtin_amdgcn_cosf(f1);
                size_t base = (size_t)t * 64 + llo;
                outp[base]      = f2b((vn[0] * cs0 - vn[2] * sn0) * mult);
                outp[base + 16] = f2b((vn[1] * cs1 - vn[3] * sn1) * mult);
                outp[base + 32] = f2b((vn[2] * cs0 + vn[0] * sn0) * mult);
                outp[base + 48] = f2b((vn[3] * cs1 + vn[1] * sn1) * mult);
            }
    } else {
        // V: write transposed tile directly: vt[b][kv][tile][d(64)][t(64)]
        const int kv = (col0 - 2560) >> 6;
        const int tile = tb >> 6;   // rm 64-aligned -> one tile per wave
        short* dst = vt + ((size_t)(b * 8 + kv) * 32 + tile) * 4096;
#pragma unroll
        for (int i = 0; i < 4; ++i)
#pragma unroll
            for (int j = 0; j < 4; ++j) {
                short4v p4 = {f2b(acc[i][j][0]), f2b(acc[i][j][1]),
                              f2b(acc[i][j][2]), f2b(acc[i][j][3])};
                *reinterpret_cast<short4v*>(
                    &dst[(j * 16 + llo) * 64 + i * 16 + lhi * 4]) = p4;
            }
    }
}

// ---------------------------------------------------------------------------
// GEMM (output projection): C(MxN,f32) = A(MxK,bf16) * Bt(NxK,bf16)^T
// 128x128 tile, BK=64 (64 KB LDS -> exactly 2 blocks/CU, grid 512 = full
// co-residency, 32 MFMA per barrier-pair), counted vmcnt(8), XOR
// chunk-swizzle (chunk ^= row&7, conflict-free).
// ---------------------------------------------------------------------------
template <typename CT>
__global__ __launch_bounds__(256) void gemm_bt(const short* __restrict__ A,
                                               const short* __restrict__ Bt,
                                               CT* __restrict__ C, int M, int N, int K) {
    __shared__ __align__(16) short sA[2][128 * 64];
    __shared__ __align__(16) short sB[2][128 * 64];

    const int tid = threadIdx.x;
    const int wave = tid >> 6, lane = tid & 63;
    const int lhi = lane >> 4, llo = lane & 15;
    int bx = blockIdx.x, by = blockIdx.y;
    xcd_swizzle(gridDim.x, bx, by);
    const int bm = by * 128, bn = bx * 128;
    const int wm = (wave >> 1) * 64, wn = (wave & 1) * 64;

    const short* apt[4];
    const short* bpt[4];
#pragma unroll
    for (int l = 0; l < 4; ++l) {
        int c = l * 256 + tid;
        int r = c >> 3, ck = (c & 7) ^ (r & 7);
        apt[l] = A + (size_t)(bm + r) * K + ck * 8;
        bpt[l] = Bt + (size_t)(bn + r) * K + ck * 8;
    }

    f32x4 acc[4][4] = {};

#pragma unroll
    for (int l = 0; l < 4; ++l) {
        GLOAD16(apt[l], &sA[0][(l * 256 + tid) * 8]);
        GLOAD16(bpt[l], &sB[0][(l * 256 + tid) * 8]);
    }
    int c = 0;
    const int co0 = ((lhi ^ (llo & 7)) << 3);
    const int co1 = (((4 + lhi) ^ (llo & 7)) << 3);

#pragma unroll 1
    for (int k0 = 0; k0 < K; k0 += 64) {
        if (k0 + 64 < K) {
            const int kn = k0 + 64;
#pragma unroll
            for (int l = 0; l < 4; ++l) {
                GLOAD16(apt[l] + kn, &sA[c ^ 1][(l * 256 + tid) * 8]);
                GLOAD16(bpt[l] + kn, &sB[c ^ 1][(l * 256 + tid) * 8]);
            }
            asm volatile("s_waitcnt vmcnt(8)" ::: "memory");
        } else {
            asm volatile("s_waitcnt vmcnt(0)" ::: "memory");
        }
        __builtin_amdgcn_s_barrier();
        asm volatile("" ::: "memory");

#pragma unroll
        for (int kk = 0; kk < 2; ++kk) {
            const int co = kk ? co1 : co0;
            bf16x8 af[4], bf[4];
#pragma unroll
            for (int i = 0; i < 4; ++i)
                af[i] = *reinterpret_cast<const bf16x8*>(&sA[c][(wm + i * 16 + llo) * 64 + co]);
#pragma unroll
            for (int j = 0; j < 4; ++j)
                bf[j] = *reinterpret_cast<const bf16x8*>(&sB[c][(wn + j * 16 + llo) * 64 + co]);
#pragma unroll
            for (int i = 0; i < 4; ++i)
#pragma unroll
                for (int j = 0; j < 4; ++j)
                    acc[i][j] = __builtin_amdgcn_mfma_f32_16x16x32_bf16(af[i], bf[j], acc[i][j], 0, 0, 0);
        }

        asm volatile("" ::: "memory");
        __builtin_amdgcn_s_barrier();
        c ^= 1;
    }

#pragma unroll
    for (int i = 0; i < 4; ++i)
#pragma unroll
        for (int j = 0; j < 4; ++j)
#pragma unroll
            for (int r = 0; r < 4; ++r) {
                size_t idx = (size_t)(bm + wm + i * 16 + lhi * 4 + r) * N + bn + wn + j * 16 + llo;
                if constexpr (sizeof(CT) == 2)
                    C[idx] = f2b(acc[i][j][r]);
                else
                    C[idx] = acc[i][j][r];
            }
}

// ---------------------------------------------------------------------------
// Flash attention, causal GQA, swapped-QK^T form, double-buffered K/V,
// defer-max online softmax.  8 thin waves x 16 q-rows (512 thr) per 128-row
// q-tile: halves the per-wave serial chain, 24 waves/CU (LDS 50.4KB).
// grid (64 hb, 16 qt-rank), longest q-tiles dispatched first (LPT).
// ---------------------------------------------------------------------------
__global__ __launch_bounds__(512) void attn_fwd(const short* __restrict__ Qb,
                                                const short* __restrict__ Kb,
                                                const short* __restrict__ Vt,
                                                short* __restrict__ Ob) {
    __shared__ __align__(16) short sK[2][64 * 64];
    __shared__ __align__(16) short sV[2][64 * 64];
    __shared__ __align__(16) short sP[8][16 * 72];

    const int hb = blockIdx.x;           // h = hb & 31, b = hb >> 5
    const int qt = 15 - (int)blockIdx.y; // y=0 -> longest (qt=15) first
    const int h = hb & 31, b = hb >> 5;
    const int kvh = h >> 2;
    const int tid = threadIdx.x, wave = tid >> 6, lane = tid & 63;
    const int lhi = lane >> 4, llo = lane & 15;

    const short* Qp = Qb + (size_t)(b * Hc + h) * Tc * 64;
    const short* Kp = Kb + (size_t)(b * KVc + kvh) * Tc * 64;
    const short* Vp = Vt + (size_t)(b * KVc + kvh) * 32 * 4096;

    // staging: 512 threads cover one 64x64 tile; 1 K + 1 V GLOAD16 each
    const int srow = tid >> 3, sslot = tid & 7;
    const int soff = (sslot ^ (srow & 7)) * 8;

    const int Q0 = qt * 128 + wave * 16;     // this wave's 16 q rows
    const int ktmax_w = (Q0 + 15) >> 6;
    const int nkt = 2 * qt + 2;

    bf16x8 qf[2];
#pragma unroll
    for (int kk = 0; kk < 2; ++kk)
        qf[kk] = *reinterpret_cast<const bf16x8*>(
            Qp + (size_t)(Q0 + llo) * 64 + kk * 32 + lhi * 8);

    f32x4 o[4] = {};
    float mreg = -1e30f;
    float lreg = 0.f;

    {
        GLOAD16(Kp + (size_t)srow * 64 + soff, &sK[0][tid * 8]);
        GLOAD16(Vp + (size_t)srow * 64 + soff, &sV[0][tid * 8]);
    }
    int c = 0;

#pragma unroll 1
    for (int kt = 0; kt < nkt; ++kt) {
        const bool has_next = (kt + 1) < nkt;
        if (has_next) {
            const size_t kbase = (size_t)(kt + 1) * 4096;
            GLOAD16(Kp + kbase + srow * 64 + soff, &sK[c ^ 1][tid * 8]);
            GLOAD16(Vp + kbase + srow * 64 + soff, &sV[c ^ 1][tid * 8]);
            asm volatile("s_waitcnt vmcnt(2)" ::: "memory");
        } else {
            asm volatile("s_waitcnt vmcnt(0)" ::: "memory");
        }
        __builtin_amdgcn_s_barrier();
        asm volatile("" ::: "memory");  // keep ds_reads below the barrier

        if (kt <= ktmax_w) {
            const short* sKc = sK[c];
            const short* sVc = sV[c];
            // S^T = K Q^T : st[n] has C[kv=16n+4lhi+r][q=llo]
            f32x4 st[4];
            __builtin_amdgcn_s_setprio(1);
#pragma unroll
            for (int n = 0; n < 4; ++n) {
                int krow = n * 16 + llo;
                bf16x8 ka0 = *reinterpret_cast<const bf16x8*>(
                    &sKc[krow * 64 + ((lhi ^ (krow & 7)) << 3)]);
                bf16x8 ka1 = *reinterpret_cast<const bf16x8*>(
                    &sKc[krow * 64 + (((4 + lhi) ^ (krow & 7)) << 3)]);
                f32x4 z = {0.f, 0.f, 0.f, 0.f};
                st[n] = __builtin_amdgcn_mfma_f32_16x16x32_bf16(ka0, qf[0], z, 0, 0, 0);
                st[n] = __builtin_amdgcn_mfma_f32_16x16x32_bf16(ka1, qf[1], st[n], 0, 0, 0);
            }
            __builtin_amdgcn_s_setprio(0);
            if (kt == ktmax_w) {  // causal mask (diagonal region only)
                int qg = Q0 + llo;
#pragma unroll
                for (int n = 0; n < 4; ++n)
#pragma unroll
                    for (int r = 0; r < 4; ++r) {
                        int kvg = kt * 64 + n * 16 + lhi * 4 + r;
                        if (kvg > qg) st[n][r] = -1e30f;
                    }
            }
            // per-row tile max (each lane owns row q = Q0 + llo)
            float r0 = fmaxf(fmaxf(st[0][0], st[0][1]), fmaxf(st[0][2], st[0][3]));
            float r1 = fmaxf(fmaxf(st[1][0], st[1][1]), fmaxf(st[1][2], st[1][3]));
            float r2 = fmaxf(fmaxf(st[2][0], st[2][1]), fmaxf(st[2][2], st[2][3]));
            float r3 = fmaxf(fmaxf(st[3][0], st[3][1]), fmaxf(st[3][2], st[3][3]));
            float pm = fmaxf(fmaxf(r0, r1), fmaxf(r2, r3));
            pm = fmaxf(pm, __shfl_xor(pm, 16));
            pm = fmaxf(pm, __shfl_xor(pm, 32));
            // defer-max: only rescale when tile max grew past running max + 8
            bool defer = __all(pm - mreg <= 8.f);
            if (!defer) {
                float mn = fmaxf(mreg, pm);
                float alpha = __builtin_amdgcn_exp2f(mreg - mn);
                mreg = mn;
                lreg *= alpha;
#pragma unroll
                for (int r = 0; r < 4; ++r) {
                    float ar = __shfl(alpha, lhi * 4 + r);
#pragma unroll
                    for (int j = 0; j < 4; ++j) o[j][r] *= ar;
                }
            }
            // P = exp2(S - m); row sum
            float ps = 0.f;
#pragma unroll
            for (int n = 0; n < 4; ++n)
#pragma unroll
                for (int r = 0; r < 4; ++r) {
                    float p = __builtin_amdgcn_exp2f(st[n][r] - mreg);
                    st[n][r] = p;
                    ps += p;
                }
            ps += __shfl_xor(ps, 16);
            ps += __shfl_xor(ps, 32);
            lreg += ps;
            // store P rows (16 x 64) to wave-private LDS (b64 stores)
#pragma unroll
            for (int n = 0; n < 4; ++n) {
                short4v p4 = {f2b(st[n][0]), f2b(st[n][1]), f2b(st[n][2]), f2b(st[n][3])};
                *reinterpret_cast<short4v*>(&sP[wave][llo * 72 + n * 16 + lhi * 4]) = p4;
            }
            // O += P V
            __builtin_amdgcn_s_setprio(1);
#pragma unroll
            for (int kk = 0; kk < 2; ++kk) {
                bf16x8 pa = *reinterpret_cast<const bf16x8*>(
                    &sP[wave][llo * 72 + kk * 32 + lhi * 8]);
#pragma unroll
                for (int j = 0; j < 4; ++j) {
                    int vrow = j * 16 + llo;
                    bf16x8 vf = *reinterpret_cast<const bf16x8*>(
                        &sVc[vrow * 64 + ((((kk * 4) + lhi) ^ (vrow & 7)) << 3)]);
                    o[j] = __builtin_amdgcn_mfma_f32_16x16x32_bf16(pa, vf, o[j], 0, 0, 0);
                }
            }
            __builtin_amdgcn_s_setprio(0);
        }
        asm volatile("" ::: "memory");  // keep ds_reads above the barrier
        __builtin_amdgcn_s_barrier();
        c ^= 1;
    }

    // epilogue: normalize, store bf16 (B,T,H*64)
    {
        float inv = 1.0f / lreg;
#pragma unroll
        for (int r = 0; r < 4; ++r) {
            float ivr = __shfl(inv, lhi * 4 + r);
            int qrow = Q0 + lhi * 4 + r;
#pragma unroll
            for (int j = 0; j < 4; ++j)
                Ob[((size_t)(b * Tc + qrow)) * 2048 + h * 64 + j * 16 + llo] =
                    f2b(o[j][r] * ivr);
        }
    }
}

// ---------------------------------------------------------------------------
extern "C" void kernel_launch(void* const* d_in, const int* in_sizes, int n_in,
                              void* d_out, int out_size, void* d_ws, size_t ws_size,
                              hipStream_t stream) {
    const float* x  = (const float*)d_in[0];
    const float* Wq = (const float*)d_in[1];
    const float* Wk = (const float*)d_in[2];
    const float* Wv = (const float*)d_in[3];
    const float* Wo = (const float*)d_in[4];
    const float* qs = (const float*)d_in[5];
    const float* ks = (const float*)d_in[6];
    float* out = (float*)d_out;

    char* w = (char*)d_ws;
    short* xb    = (short*)(w);                 // 16,777,216  (later: ob)
    short* WqkvT = (short*)(w + 16777216);      // 12,582,912
    short* WoT   = (short*)(w + 29360128);      //  8,388,608
    short* vt    = (short*)(w + 37748736);      //  8,388,608  (B,KV,32,64,64)
    short* qb    = (short*)(w + 62914560);      // 16,777,216
    short* kb    = (short*)(w + 79691776);      //  4,194,304
    short* ob    = xb;                          // alias (xb dead after proj)

    dim3 blk(256);
    // prep: x convert + all weight transposes in one launch
    prep_all<<<dim3(32, 32, 5), blk, 0, stream>>>(x, Wq, Wk, Wv, Wo, xb, WqkvT, WoT);
    // fused QKV projection + RMSNorm/RoPE epilogue + V-transpose -> qb, kb, vt
    gemm_proj<<<dim3(24, 32), blk, 0, stream>>>(xb, WqkvT, qs, ks, qb, kb, vt);
    // flash attention: 1024 blocks x 512 thr, longest q-tiles first (LPT)
    attn_fwd<<<dim3(64, 16), dim3(512), 0, stream>>>(qb, kb, vt, ob);
    // output projection (f32 out, BK=64: 2 blocks/CU exact co-residency)
    gemm_bt<float><<<dim3(16, 32), blk, 0, stream>>>(ob, WoT, out, 4096, 2048, 2048);
}

// Round 18
// 198.783 us; speedup vs baseline: 1.0511x; 1.0042x over previous
//
#include <hip/hip_runtime.h>
#include <hip/hip_bf16.h>

typedef __attribute__((ext_vector_type(4))) float f32x4;
typedef __attribute__((ext_vector_type(8))) short bf16x8;
typedef __attribute__((ext_vector_type(4))) short short4v;

#define DEVI __device__ __forceinline__

constexpr int Bc = 2, Tc = 2048, Dc = 2048, Hc = 32, KVc = 8, HDc = 64;
constexpr int GRP = Hc / KVc;  // 4
constexpr float EPSc = 1e-6f;
// SCALE * log2(e) folded into Q so softmax uses exp2
constexpr float QMULT = 0.125f * 1.4426950408889634f;
constexpr float INV2PI = 0.15915494309189535f;
constexpr float ROPE_C = 0.41524101186092029f;  // log2(10000)/32

DEVI short f2b(float f) {
    __hip_bfloat16 h = __float2bfloat16(f);
    short s;
    __builtin_memcpy(&s, &h, sizeof(short));
    return s;
}
DEVI float b2f(short s) {
    unsigned int u = ((unsigned int)(unsigned short)s) << 16;
    float f;
    __builtin_memcpy(&f, &u, sizeof(float));
    return f;
}

#define GLOAD16(g, l)                                                        \
    __builtin_amdgcn_global_load_lds(                                        \
        (const __attribute__((address_space(1))) void*)(g),                  \
        (__attribute__((address_space(3))) void*)(l), 16, 0, 0)

// ---------------------------------------------------------------------------
// prep: weight transposes f32 (2048 x C) -> bf16 (C x 2048) (z=0..3) and
// x f32 -> bf16 convert (z=4), one launch.  grid (32, 32, 5).
// ---------------------------------------------------------------------------
__global__ __launch_bounds__(256) void prep_all(const float* __restrict__ x,
                                                const float* __restrict__ Wq,
                                                const float* __restrict__ Wk,
                                                const float* __restrict__ Wv,
                                                const float* __restrict__ Wo,
                                                short* __restrict__ xb,
                                                short* __restrict__ WqkvT,
                                                short* __restrict__ WoT) {
    const int z = blockIdx.z;
    if (z == 4) {  // convert x: 8.4M elems, 1024 blocks, 4 passes of 8/thread
        size_t base = ((size_t)(blockIdx.y * 32 + blockIdx.x) * 256 + threadIdx.x) * 8;
#pragma unroll
        for (int p = 0; p < 4; ++p) {
            size_t i = base + (size_t)p * 2097152;
            float4 a = *reinterpret_cast<const float4*>(x + i);
            float4 b = *reinterpret_cast<const float4*>(x + i + 4);
            bf16x8 o = {f2b(a.x), f2b(a.y), f2b(a.z), f2b(a.w),
                        f2b(b.x), f2b(b.y), f2b(b.z), f2b(b.w)};
            *reinterpret_cast<bf16x8*>(xb + i) = o;
        }
        return;
    }
    const float* src;
    short* dst;
    int C;
    if (z == 0)      { src = Wq; dst = WqkvT;                          C = 2048; }
    else if (z == 1) { src = Wk; dst = WqkvT + (size_t)2048 * 2048;    C = 512; }
    else if (z == 2) { src = Wv; dst = WqkvT + (size_t)2560 * 2048;    C = 512; }
    else             { src = Wo; dst = WoT;                            C = 2048; }
    const int n0 = blockIdx.x * 64, k0 = blockIdx.y * 64;
    if (n0 >= C) return;

    __shared__ __align__(16) short t[64][72];
    const int rl = threadIdx.x >> 2, q = threadIdx.x & 3;
#pragma unroll
    for (int jj = 0; jj < 4; ++jj) {
        float4 v = *reinterpret_cast<const float4*>(src + (size_t)(k0 + rl) * C + n0 + q * 16 + jj * 4);
        short4v s = {f2b(v.x), f2b(v.y), f2b(v.z), f2b(v.w)};
        *reinterpret_cast<short4v*>(&t[rl][q * 16 + jj * 4]) = s;
    }
    __syncthreads();
    alignas(16) short buf[16];
#pragma unroll
    for (int e = 0; e < 16; ++e) buf[e] = t[q * 16 + e][rl];
    short* d = dst + (size_t)(n0 + rl) * 2048 + k0 + q * 16;
    *reinterpret_cast<int4*>(d) = reinterpret_cast<int4*>(buf)[0];
    *reinterpret_cast<int4*>(d + 8) = reinterpret_cast<int4*>(buf)[1];
}

// bijective XCD swizzle of flattened block id (nwg % 8 == 0)
DEVI void xcd_swizzle(int nx, int& bx, int& by) {
    int nwg = nx * gridDim.y;
    int fb = by * nx + bx;
    int cpx = nwg >> 3;
    int swz = (fb & 7) * cpx + (fb >> 3);
    by = swz / nx;
    bx = swz - by * nx;
}

// ---------------------------------------------------------------------------
// QKV-projection GEMM with fused RMSNorm+RoPE epilogue and fused V-transpose.
// C(4096x3072) = xb(4096x2048) * WqkvT(3072x2048)^T, 128x128 tile, BK=32,
// TRIPLE-buffered LDS (48 KB -> 3 blocks/CU = grid residency), counted
// vmcnt(8) = 2 K-tiles in flight, XOR chunk-swizzle (chunk ^= (row>>1)&3,
// conflict-free).  256 thr (4 waves 2x2 of 64x64); wave cols = one head.
// Epilogue: cols<2048 -> RMSNorm(qs)+RoPE+QMULT -> qb (B,H,T,64)
//           cols 2048-2559 -> RMSNorm(ks)+RoPE -> kb (B,KV,T,64)
//           cols>=2560 -> transposed bf16 tiles vt[b][kv][tile][d64][t64]
// ---------------------------------------------------------------------------
__global__ __launch_bounds__(256) void gemm_proj(const short* __restrict__ A,
                                                 const short* __restrict__ Bt,
                                                 const float* __restrict__ qs,
                                                 const float* __restrict__ ks,
                                                 short* __restrict__ qb,
                                                 short* __restrict__ kb,
                                                 short* __restrict__ vt) {
    constexpr int K = 2048;
    constexpr int NT = K / 32;  // 64 K-tiles
    __shared__ __align__(16) short sA[3][128 * 32];
    __shared__ __align__(16) short sB[3][128 * 32];

    const int tid = threadIdx.x;
    const int wave = tid >> 6, lane = tid & 63;
    const int lhi = lane >> 4, llo = lane & 15;
    int bx = blockIdx.x, by = blockIdx.y;
    xcd_swizzle(24, bx, by);
    const int bm = by * 128, bn = bx * 128;
    const int wm = (wave >> 1) * 64, wn = (wave & 1) * 64;

    const short* apt[2];
    const short* bpt[2];
#pragma unroll
    for (int l = 0; l < 2; ++l) {
        int c = l * 256 + tid;
        int r = c >> 2, ck = (c & 3) ^ ((r >> 1) & 3);
        apt[l] = A + (size_t)(bm + r) * K + ck * 8;
        bpt[l] = Bt + (size_t)(bn + r) * K + ck * 8;
    }

    f32x4 acc[4][4] = {};

    // prologue: stage K-tiles 0 and 1 into bufs 0, 1
#pragma unroll
    for (int tt = 0; tt < 2; ++tt)
#pragma unroll
        for (int l = 0; l < 2; ++l) {
            GLOAD16(apt[l] + tt * 32, &sA[tt][(l * 256 + tid) * 8]);
            GLOAD16(bpt[l] + tt * 32, &sB[tt][(l * 256 + tid) * 8]);
        }
    int c = 0;
    const int co = ((lhi ^ ((llo >> 1) & 3)) << 3);

#pragma unroll 1
    for (int t = 0; t < NT; ++t) {
        if (t + 2 < NT) {
            const int kn = (t + 2) * 32;
            const int nb = (c + 2) % 3;
#pragma unroll
            for (int l = 0; l < 2; ++l) {
                GLOAD16(apt[l] + kn, &sA[nb][(l * 256 + tid) * 8]);
                GLOAD16(bpt[l] + kn, &sB[nb][(l * 256 + tid) * 8]);
            }
            asm volatile("s_waitcnt vmcnt(8)" ::: "memory");
        } else if (t + 1 < NT) {
            asm volatile("s_waitcnt vmcnt(4)" ::: "memory");
        } else {
            asm volatile("s_waitcnt vmcnt(0)" ::: "memory");
        }
        __builtin_amdgcn_s_barrier();
        asm volatile("" ::: "memory");

        bf16x8 af[4], bf[4];
#pragma unroll
        for (int i = 0; i < 4; ++i)
            af[i] = *reinterpret_cast<const bf16x8*>(&sA[c][(wm + i * 16 + llo) * 32 + co]);
#pragma unroll
        for (int j = 0; j < 4; ++j)
            bf[j] = *reinterpret_cast<const bf16x8*>(&sB[c][(wn + j * 16 + llo) * 32 + co]);
#pragma unroll
        for (int i = 0; i < 4; ++i)
#pragma unroll
            for (int j = 0; j < 4; ++j)
                acc[i][j] = __builtin_amdgcn_mfma_f32_16x16x32_bf16(af[i], bf[j], acc[i][j], 0, 0, 0);

        asm volatile("" ::: "memory");
        __builtin_amdgcn_s_barrier();
        c = (c + 1) % 3;
    }

    // ---- fused epilogue ----
    const int rm = bm + wm;       // wave's first output row (64-aligned)
    const int b = rm >> 11;
    const int tb = rm & 2047;
    const int col0 = bn + wn;     // wave's first output col (64-aligned)

    if (col0 < 2560) {
        const bool isq = col0 < 2048;
        const float* scale = isq ? qs : ks;
        const float mult = isq ? QMULT : 1.0f;
        float scl[4];
#pragma unroll
        for (int j = 0; j < 4; ++j) scl[j] = scale[j * 16 + llo];
        short* outp;
        if (isq)
            outp = qb + (size_t)(b * Hc + (col0 >> 6)) * 2048 * 64;
        else
            outp = kb + (size_t)(b * KVc + ((col0 - 2048) >> 6)) * 2048 * 64;
        // per-lane RoPE revolution factors: i_rope = (j&1)*16 + llo
        const float ir0 = INV2PI * exp2f(-ROPE_C * (float)llo);
        const float ir1 = INV2PI * exp2f(-ROPE_C * (float)(16 + llo));
#pragma unroll
        for (int i = 0; i < 4; ++i)
#pragma unroll
            for (int r = 0; r < 4; ++r) {
                float ss = 0.f;
#pragma unroll
                for (int j = 0; j < 4; ++j) ss += acc[i][j][r] * acc[i][j][r];
                ss += __shfl_xor(ss, 1);
                ss += __shfl_xor(ss, 2);
                ss += __shfl_xor(ss, 4);
                ss += __shfl_xor(ss, 8);
                float rinv = 1.0f / sqrtf(ss * (1.0f / 64.0f) + EPSc);
                float vn[4];
#pragma unroll
                for (int j = 0; j < 4; ++j) vn[j] = acc[i][j][r] * rinv * scl[j];
                const int t = tb + i * 16 + lhi * 4 + r;
                float f0 = (float)t * ir0;
                f0 -= floorf(f0);
                float f1 = (float)t * ir1;
                f1 -= floorf(f1);
                float sn0 = __builtin_amdgcn_sinf(f0), cs0 = __builtin_amdgcn_cosf(f0);
                float sn1 = __builtin_amdgcn_sinf(f1), cs1 = __builtin_amdgcn_cosf(f1);
                size_t base = (size_t)t * 64 + llo;
                outp[base]      = f2b((vn[0] * cs0 - vn[2] * sn0) * mult);
                outp[base + 16] = f2b((vn[1] * cs1 - vn[3] * sn1) * mult);
                outp[base + 32] = f2b((vn[2] * cs0 + vn[0] * sn0) * mult);
                outp[base + 48] = f2b((vn[3] * cs1 + vn[1] * sn1) * mult);
            }
    } else {
        // V: write transposed tile directly: vt[b][kv][tile][d(64)][t(64)]
        const int kv = (col0 - 2560) >> 6;
        const int tile = tb >> 6;   // rm 64-aligned -> one tile per wave
        short* dst = vt + ((size_t)(b * 8 + kv) * 32 + tile) * 4096;
#pragma unroll
        for (int i = 0; i < 4; ++i)
#pragma unroll
            for (int j = 0; j < 4; ++j) {
                short4v p4 = {f2b(acc[i][j][0]), f2b(acc[i][j][1]),
                              f2b(acc[i][j][2]), f2b(acc[i][j][3])};
                *reinterpret_cast<short4v*>(
                    &dst[(j * 16 + llo) * 64 + i * 16 + lhi * 4]) = p4;
            }
    }
}

// ---------------------------------------------------------------------------
// GEMM (output projection): C(MxN,f32) = A(MxK,bf16) * Bt(NxK,bf16)^T
// 128x128 tile, BK=64 (64 KB LDS -> exactly 2 blocks/CU, grid 512 = full
// co-residency, 32 MFMA per barrier-pair), counted vmcnt(8), XOR
// chunk-swizzle (chunk ^= row&7, conflict-free).
// ---------------------------------------------------------------------------
template <typename CT>
__global__ __launch_bounds__(256) void gemm_bt(const short* __restrict__ A,
                                               const short* __restrict__ Bt,
                                               CT* __restrict__ C, int M, int N, int K) {
    __shared__ __align__(16) short sA[2][128 * 64];
    __shared__ __align__(16) short sB[2][128 * 64];

    const int tid = threadIdx.x;
    const int wave = tid >> 6, lane = tid & 63;
    const int lhi = lane >> 4, llo = lane & 15;
    int bx = blockIdx.x, by = blockIdx.y;
    xcd_swizzle(gridDim.x, bx, by);
    const int bm = by * 128, bn = bx * 128;
    const int wm = (wave >> 1) * 64, wn = (wave & 1) * 64;

    const short* apt[4];
    const short* bpt[4];
#pragma unroll
    for (int l = 0; l < 4; ++l) {
        int c = l * 256 + tid;
        int r = c >> 3, ck = (c & 7) ^ (r & 7);
        apt[l] = A + (size_t)(bm + r) * K + ck * 8;
        bpt[l] = Bt + (size_t)(bn + r) * K + ck * 8;
    }

    f32x4 acc[4][4] = {};

#pragma unroll
    for (int l = 0; l < 4; ++l) {
        GLOAD16(apt[l], &sA[0][(l * 256 + tid) * 8]);
        GLOAD16(bpt[l], &sB[0][(l * 256 + tid) * 8]);
    }
    int c = 0;
    const int co0 = ((lhi ^ (llo & 7)) << 3);
    const int co1 = (((4 + lhi) ^ (llo & 7)) << 3);

#pragma unroll 1
    for (int k0 = 0; k0 < K; k0 += 64) {
        if (k0 + 64 < K) {
            const int kn = k0 + 64;
#pragma unroll
            for (int l = 0; l < 4; ++l) {
                GLOAD16(apt[l] + kn, &sA[c ^ 1][(l * 256 + tid) * 8]);
                GLOAD16(bpt[l] + kn, &sB[c ^ 1][(l * 256 + tid) * 8]);
            }
            asm volatile("s_waitcnt vmcnt(8)" ::: "memory");
        } else {
            asm volatile("s_waitcnt vmcnt(0)" ::: "memory");
        }
        __builtin_amdgcn_s_barrier();
        asm volatile("" ::: "memory");

#pragma unroll
        for (int kk = 0; kk < 2; ++kk) {
            const int co = kk ? co1 : co0;
            bf16x8 af[4], bf[4];
#pragma unroll
            for (int i = 0; i < 4; ++i)
                af[i] = *reinterpret_cast<const bf16x8*>(&sA[c][(wm + i * 16 + llo) * 64 + co]);
#pragma unroll
            for (int j = 0; j < 4; ++j)
                bf[j] = *reinterpret_cast<const bf16x8*>(&sB[c][(wn + j * 16 + llo) * 64 + co]);
#pragma unroll
            for (int i = 0; i < 4; ++i)
#pragma unroll
                for (int j = 0; j < 4; ++j)
                    acc[i][j] = __builtin_amdgcn_mfma_f32_16x16x32_bf16(af[i], bf[j], acc[i][j], 0, 0, 0);
        }

        asm volatile("" ::: "memory");
        __builtin_amdgcn_s_barrier();
        c ^= 1;
    }

#pragma unroll
    for (int i = 0; i < 4; ++i)
#pragma unroll
        for (int j = 0; j < 4; ++j)
#pragma unroll
            for (int r = 0; r < 4; ++r) {
                size_t idx = (size_t)(bm + wm + i * 16 + lhi * 4 + r) * N + bn + wn + j * 16 + llo;
                if constexpr (sizeof(CT) == 2)
                    C[idx] = f2b(acc[i][j][r]);
                else
                    C[idx] = acc[i][j][r];
            }
}

// ---------------------------------------------------------------------------
// Flash attention, causal GQA, swapped-QK^T form, double-buffered K/V,
// defer-max online softmax.  8 thin waves x 16 q-rows (512 thr) per 128-row
// q-tile: halves the per-wave serial chain, 24 waves/CU (LDS 50.4KB).
// grid (64 hb, 16 qt-rank), longest q-tiles dispatched first (LPT).
// ---------------------------------------------------------------------------
__global__ __launch_bounds__(512) void attn_fwd(const short* __restrict__ Qb,
                                                const short* __restrict__ Kb,
                                                const short* __restrict__ Vt,
                                                short* __restrict__ Ob) {
    __shared__ __align__(16) short sK[2][64 * 64];
    __shared__ __align__(16) short sV[2][64 * 64];
    __shared__ __align__(16) short sP[8][16 * 72];

    const int hb = blockIdx.x;           // h = hb & 31, b = hb >> 5
    const int qt = 15 - (int)blockIdx.y; // y=0 -> longest (qt=15) first
    const int h = hb & 31, b = hb >> 5;
    const int kvh = h >> 2;
    const int tid = threadIdx.x, wave = tid >> 6, lane = tid & 63;
    const int lhi = lane >> 4, llo = lane & 15;

    const short* Qp = Qb + (size_t)(b * Hc + h) * Tc * 64;
    const short* Kp = Kb + (size_t)(b * KVc + kvh) * Tc * 64;
    const short* Vp = Vt + (size_t)(b * KVc + kvh) * 32 * 4096;

    // staging: 512 threads cover one 64x64 tile; 1 K + 1 V GLOAD16 each
    const int srow = tid >> 3, sslot = tid & 7;
    const int soff = (sslot ^ (srow & 7)) * 8;

    const int Q0 = qt * 128 + wave * 16;     // this wave's 16 q rows
    const int ktmax_w = (Q0 + 15) >> 6;
    const int nkt = 2 * qt + 2;

    bf16x8 qf[2];
#pragma unroll
    for (int kk = 0; kk < 2; ++kk)
        qf[kk] = *reinterpret_cast<const bf16x8*>(
            Qp + (size_t)(Q0 + llo) * 64 + kk * 32 + lhi * 8);

    f32x4 o[4] = {};
    float mreg = -1e30f;
    float lreg = 0.f;

    {
        GLOAD16(Kp + (size_t)srow * 64 + soff, &sK[0][tid * 8]);
        GLOAD16(Vp + (size_t)srow * 64 + soff, &sV[0][tid * 8]);
    }
    int c = 0;

#pragma unroll 1
    for (int kt = 0; kt < nkt; ++kt) {
        const bool has_next = (kt + 1) < nkt;
        if (has_next) {
            const size_t kbase = (size_t)(kt + 1) * 4096;
            GLOAD16(Kp + kbase + srow * 64 + soff, &sK[c ^ 1][tid * 8]);
            GLOAD16(Vp + kbase + srow * 64 + soff, &sV[c ^ 1][tid * 8]);
            asm volatile("s_waitcnt vmcnt(2)" ::: "memory");
        } else {
            asm volatile("s_waitcnt vmcnt(0)" ::: "memory");
        }
        __builtin_amdgcn_s_barrier();
        asm volatile("" ::: "memory");  // keep ds_reads below the barrier

        if (kt <= ktmax_w) {
            const short* sKc = sK[c];
            const short* sVc = sV[c];
            // S^T = K Q^T : st[n] has C[kv=16n+4lhi+r][q=llo]
            f32x4 st[4];
            __builtin_amdgcn_s_setprio(1);
#pragma unroll
            for (int n = 0; n < 4; ++n) {
                int krow = n * 16 + llo;
                bf16x8 ka0 = *reinterpret_cast<const bf16x8*>(
                    &sKc[krow * 64 + ((lhi ^ (krow & 7)) << 3)]);
                bf16x8 ka1 = *reinterpret_cast<const bf16x8*>(
                    &sKc[krow * 64 + (((4 + lhi) ^ (krow & 7)) << 3)]);
                f32x4 z = {0.f, 0.f, 0.f, 0.f};
                st[n] = __builtin_amdgcn_mfma_f32_16x16x32_bf16(ka0, qf[0], z, 0, 0, 0);
                st[n] = __builtin_amdgcn_mfma_f32_16x16x32_bf16(ka1, qf[1], st[n], 0, 0, 0);
            }
            __builtin_amdgcn_s_setprio(0);
            if (kt == ktmax_w) {  // causal mask (diagonal region only)
                int qg = Q0 + llo;
#pragma unroll
                for (int n = 0; n < 4; ++n)
#pragma unroll
                    for (int r = 0; r < 4; ++r) {
                        int kvg = kt * 64 + n * 16 + lhi * 4 + r;
                        if (kvg > qg) st[n][r] = -1e30f;
                    }
            }
            // per-row tile max (each lane owns row q = Q0 + llo)
            float r0 = fmaxf(fmaxf(st[0][0], st[0][1]), fmaxf(st[0][2], st[0][3]));
            float r1 = fmaxf(fmaxf(st[1][0], st[1][1]), fmaxf(st[1][2], st[1][3]));
            float r2 = fmaxf(fmaxf(st[2][0], st[2][1]), fmaxf(st[2][2], st[2][3]));
            float r3 = fmaxf(fmaxf(st[3][0], st[3][1]), fmaxf(st[3][2], st[3][3]));
            float pm = fmaxf(fmaxf(r0, r1), fmaxf(r2, r3));
            pm = fmaxf(pm, __shfl_xor(pm, 16));
            pm = fmaxf(pm, __shfl_xor(pm, 32));
            // defer-max: only rescale when tile max grew past running max + 8
            bool defer = __all(pm - mreg <= 8.f);
            if (!defer) {
                float mn = fmaxf(mreg, pm);
                float alpha = __builtin_amdgcn_exp2f(mreg - mn);
                mreg = mn;
                lreg *= alpha;
#pragma unroll
                for (int r = 0; r < 4; ++r) {
                    float ar = __shfl(alpha, lhi * 4 + r);
#pragma unroll
                    for (int j = 0; j < 4; ++j) o[j][r] *= ar;
                }
            }
            // P = exp2(S - m); row sum
            float ps = 0.f;
#pragma unroll
            for (int n = 0; n < 4; ++n)
#pragma unroll
                for (int r = 0; r < 4; ++r) {
                    float p = __builtin_amdgcn_exp2f(st[n][r] - mreg);
                    st[n][r] = p;
                    ps += p;
                }
            ps += __shfl_xor(ps, 16);
            ps += __shfl_xor(ps, 32);
            lreg += ps;
            // store P rows (16 x 64) to wave-private LDS (b64 stores)
#pragma unroll
            for (int n = 0; n < 4; ++n) {
                short4v p4 = {f2b(st[n][0]), f2b(st[n][1]), f2b(st[n][2]), f2b(st[n][3])};
                *reinterpret_cast<short4v*>(&sP[wave][llo * 72 + n * 16 + lhi * 4]) = p4;
            }
            // O += P V
            __builtin_amdgcn_s_setprio(1);
#pragma unroll
            for (int kk = 0; kk < 2; ++kk) {
                bf16x8 pa = *reinterpret_cast<const bf16x8*>(
                    &sP[wave][llo * 72 + kk * 32 + lhi * 8]);
#pragma unroll
                for (int j = 0; j < 4; ++j) {
                    int vrow = j * 16 + llo;
                    bf16x8 vf = *reinterpret_cast<const bf16x8*>(
                        &sVc[vrow * 64 + ((((kk * 4) + lhi) ^ (vrow & 7)) << 3)]);
                    o[j] = __builtin_amdgcn_mfma_f32_16x16x32_bf16(pa, vf, o[j], 0, 0, 0);
                }
            }
            __builtin_amdgcn_s_setprio(0);
        }
        asm volatile("" ::: "memory");  // keep ds_reads above the barrier
        __builtin_amdgcn_s_barrier();
        c ^= 1;
    }

    // epilogue: normalize, store bf16 (B,T,H*64)
    {
        float inv = 1.0f / lreg;
#pragma unroll
        for (int r = 0; r < 4; ++r) {
            float ivr = __shfl(inv, lhi * 4 + r);
            int qrow = Q0 + lhi * 4 + r;
#pragma unroll
            for (int j = 0; j < 4; ++j)
                Ob[((size_t)(b * Tc + qrow)) * 2048 + h * 64 + j * 16 + llo] =
                    f2b(o[j][r] * ivr);
        }
    }
}

// ---------------------------------------------------------------------------
extern "C" void kernel_launch(void* const* d_in, const int* in_sizes, int n_in,
                              void* d_out, int out_size, void* d_ws, size_t ws_size,
                              hipStream_t stream) {
    const float* x  = (const float*)d_in[0];
    const float* Wq = (const float*)d_in[1];
    const float* Wk = (const float*)d_in[2];
    const float* Wv = (const float*)d_in[3];
    const float* Wo = (const float*)d_in[4];
    const float* qs = (const float*)d_in[5];
    const float* ks = (const float*)d_in[6];
    float* out = (float*)d_out;

    char* w = (char*)d_ws;
    short* xb    = (short*)(w);                 // 16,777,216  (later: ob)
    short* WqkvT = (short*)(w + 16777216);      // 12,582,912
    short* WoT   = (short*)(w + 29360128);      //  8,388,608
    short* vt    = (short*)(w + 37748736);      //  8,388,608  (B,KV,32,64,64)
    short* qb    = (short*)(w + 62914560);      // 16,777,216
    short* kb    = (short*)(w + 79691776);      //  4,194,304
    short* ob    = xb;                          // alias (xb dead after proj)

    dim3 blk(256);
    // prep: x convert + all weight transposes in one launch
    prep_all<<<dim3(32, 32, 5), blk, 0, stream>>>(x, Wq, Wk, Wv, Wo, xb, WqkvT, WoT);
    // fused QKV projection + RMSNorm/RoPE epilogue + V-transpose -> qb, kb, vt
    gemm_proj<<<dim3(24, 32), blk, 0, stream>>>(xb, WqkvT, qs, ks, qb, kb, vt);
    // flash attention: 1024 blocks x 512 thr, longest q-tiles first (LPT)
    attn_fwd<<<dim3(64, 16), dim3(512), 0, stream>>>(qb, kb, vt, ob);
    // output projection (f32 out, BK=64: 2 blocks/CU exact co-residency)
    gemm_bt<float><<<dim3(16, 32), blk, 0, stream>>>(ob, WoT, out, 4096, 2048, 2048);
}